// Round 3
// baseline (695.503 us; speedup 1.0000x reference)
//
#include <hip/hip_runtime.h>
#include <hip/hip_bf16.h>
#include <stdint.h>

// Problem constants
#define KK 4
#define BB 16
#define LL 4096
#define DD 512
#define HH 128
#define TPW 8   // tiles (4-position groups) per wave

typedef __attribute__((ext_vector_type(8))) short bf16x8;
typedef __attribute__((ext_vector_type(4))) float f32x4;
typedef __attribute__((ext_vector_type(4))) unsigned int u32x4;

__device__ __forceinline__ unsigned int pack_bf16(float lo, float hi) {
  unsigned int a = __float_as_uint(lo);
  unsigned int b = __float_as_uint(hi);
  a = (a + 0x7FFFu + ((a >> 16) & 1u)) >> 16;   // RNE f32->bf16
  b = (b + 0x7FFFu + ((b >> 16) & 1u)) >> 16;
  return a | (b << 16);
}

__device__ __forceinline__ void packA(f32x4 v0, f32x4 v1, bf16x8* dst) {
  u32x4 p;
  p.x = pack_bf16(v0.x, v0.y);
  p.y = pack_bf16(v0.z, v0.w);
  p.z = pack_bf16(v1.x, v1.y);
  p.w = pack_bf16(v1.z, v1.w);
  *dst = __builtin_bit_cast(bf16x8, p);
}

template <int CTRL>
__device__ __forceinline__ float qadd(float x) {
  // x + quad_perm<CTRL>(x)  — VALU-pipe cross-lane add within each 4-lane quad
  int y = __builtin_amdgcn_update_dpp(0, __float_as_int(x), CTRL, 0xF, 0xF, true);
  return x + __int_as_float(y);
}

__device__ __forceinline__ void load_lds16(const unsigned int* g, void* l) {
  __builtin_amdgcn_global_load_lds(
      (const __attribute__((address_space(1))) unsigned int*)g,
      (__attribute__((address_space(3))) unsigned int*)l, 16, 0, 0);
}

// ---------------- kernel 0a: q_bias = W_q @ vq + ln_b ----------------
__global__ void qbias_kernel(const float* __restrict__ ln_w,
                             const float* __restrict__ ln_b,
                             const float* __restrict__ vq,
                             float* __restrict__ qb) {
  int h = threadIdx.x;
  if (h < HH) {
    float acc = ln_b[h];
    const float* wq = ln_w + (size_t)h * (DD + HH) + DD;
    for (int j = 0; j < HH; ++j) acc = fmaf(wq[j], vq[j], acc);
    qb[h] = acc;
  }
}

// ---------------- kernel 0b: W_h -> fragment-ordered bf16 ----------------
// Chunk gid = (ks*8 + nt)*64 + lane holds 8 bf16 (B-fragment for MFMA):
//   element j: W[nt*16 + (lane&15)][ks*32 + (j>=4)*16 + (lane>>4)*4 + (j&3)]
// (d-permutation matches the A-side load order; applied to both operands.)
__global__ void wf_kernel(const float* __restrict__ ln_w,
                          unsigned int* __restrict__ wf) {
  int gid = blockIdx.x * 256 + threadIdx.x;   // 0..8191
  int ks = gid >> 9;
  int nt = (gid >> 6) & 7;
  int lane = gid & 63;
  int h = nt * 16 + (lane & 15);
  int cg = lane >> 4;
  const float* src = ln_w + (size_t)h * (DD + HH) + ks * 32 + cg * 4;
  f32x4 v0 = *(const f32x4*)(src);
  f32x4 v1 = *(const f32x4*)(src + 16);
  u32x4 v;
  v.x = pack_bf16(v0.x, v0.y);
  v.y = pack_bf16(v0.z, v0.w);
  v.z = pack_bf16(v1.x, v1.y);
  v.w = pack_bf16(v1.z, v1.w);
  *(u32x4*)(wf + (size_t)gid * 4) = v;
}

// ---------------- main fused kernel ----------------
// 256 blocks x 512 threads (1 block/CU, 8 waves). W_h staged once into LDS
// (128 KB), one barrier, then waves free-run over TPW=8 consecutive 4-pos
// tiles each, with next-tile A loads interleaved into the current GEMM.
// MFMA M-row m = pos*4 + k  ->  C/D: pos = lane>>4, k = acc reg j (softmax
// fully in-lane); k-weighted sum = DPP quad-perm butterfly (VALU pipe).
__global__ __launch_bounds__(512, 2) void agg_main(
    const float* __restrict__ hs, const unsigned int* __restrict__ wf,
    const float* __restrict__ qb, const float* __restrict__ vw,
    float* __restrict__ out) {
  extern __shared__ char smemW[];   // 131072 B: W fragments, linear

  const int tid = threadIdx.x;
  const int lane = tid & 63;
  const int wv = tid >> 6;          // 0..7

  // ---- stage W -> LDS (16 x 1KB chunks per wave) ----
#pragma unroll
  for (int i = 0; i < 16; ++i) {
    int chunk = i * 8 + wv;         // 0..127
    load_lds16(wf + chunk * 256 + lane * 4, smemW + chunk * 1024);
  }

  const int r = lane & 15;          // MFMA A-row index (m)
  const int cg = lane >> 4;         // d col-group (and C/D pos group)
  const int kk = r & 3;             // this lane's A rows: k
  const int pp = r >> 2;            //                     pos offset

  float qbr[8], vwr[8];
#pragma unroll
  for (int nt = 0; nt < 8; ++nt) {
    qbr[nt] = qb[nt * 16 + r];
    vwr[nt] = vw[nt * 16 + r];
  }

  __syncthreads();                  // W resident; waves independent from here

  const int g0 = blockIdx.x * (8 * TPW) + wv * TPW;  // 8 consecutive tiles

  // A base address for tile g (this lane loads row (k=kk, pos=(g&1023)*4+pp))
  auto abase = [&](int g) -> const float* {
    int b = g >> 10;
    int l = ((g & 1023) << 2) + pp;
    return hs + (((size_t)kk * BB + b) * LL + l) * DD + cg * 4;
  };

  bf16x8 aC[16], aN[16];

  // ---- prologue: load + pack tile g0 ----
  {
    const float* ab = abase(g0);
#pragma unroll
    for (int ks = 0; ks < 16; ++ks) {
      f32x4 v0 = *(const f32x4*)(ab + ks * 32);
      f32x4 v1 = *(const f32x4*)(ab + ks * 32 + 16);
      packA(v0, v1, &aC[ks]);
    }
  }

  for (int t = 0; t < TPW; ++t) {
    const int g = g0 + t;
    const bool hasNext = (t < TPW - 1);
    const float* nb = abase(hasNext ? g + 1 : g);

    f32x4 acc[8];
#pragma unroll
    for (int nt = 0; nt < 8; ++nt) acc[nt] = (f32x4){0.f, 0.f, 0.f, 0.f};

    // ---- GEMM over 16 K-steps, with interleaved next-tile prefetch ----
    f32x4 rw0[4], rw1[4];           // rotating raw buffer (static idx: unrolled)
#pragma unroll
    for (int ks = 0; ks < 16; ++ks) {
      if (hasNext) {
        if (ks >= 4) packA(rw0[ks & 3], rw1[ks & 3], &aN[ks - 4]);
        rw0[ks & 3] = *(const f32x4*)(nb + ks * 32);
        rw1[ks & 3] = *(const f32x4*)(nb + ks * 32 + 16);
      }
#pragma unroll
      for (int nt = 0; nt < 8; ++nt) {
        bf16x8 wv8 = *(const bf16x8*)(smemW + ((ks * 8 + nt) * 64 + lane) * 16);
        acc[nt] = __builtin_amdgcn_mfma_f32_16x16x32_bf16(aC[ks], wv8,
                                                          acc[nt], 0, 0, 0);
      }
    }

    // ---- scores + in-lane softmax over k ----
    // lane holds z[h = nt*16 + r][m = cg*4 + j] -> (pos = cg, k = j)
    float av;
    {
      float s[4];
#pragma unroll
      for (int j = 0; j < 4; ++j) {
        float as = 0.f;
#pragma unroll
        for (int nt = 0; nt < 8; ++nt) {
          float z = acc[nt][j] + qbr[nt];
          z = fminf(15.f, fmaxf(-15.f, z));
          float e = __expf(-2.f * z);
          float th = (1.f - e) * __builtin_amdgcn_rcpf(1.f + e);
          as = fmaf(vwr[nt], th, as);
        }
#pragma unroll
        for (int m = 1; m < 16; m <<= 1) as += __shfl_xor(as, m, 64);
        s[j] = as;
      }
      // mask dropped: uniform per-(b,l) shift is softmax-invariant
      float mx = fmaxf(fmaxf(s[0], s[1]), fmaxf(s[2], s[3]));
      float e0 = __expf(s[0] - mx), e1 = __expf(s[1] - mx);
      float e2 = __expf(s[2] - mx), e3 = __expf(s[3] - mx);
      float inv = __builtin_amdgcn_rcpf(e0 + e1 + e2 + e3);
      float a0 = e0 * inv, a1 = e1 * inv, a2 = e2 * inv, a3 = e3 * inv;
      // redistribute: this lane's A rows are (k=kk, pos=pp); source group = pp
      int srcl = (pp << 4) | r;
      float t0 = __shfl(a0, srcl, 64);
      float t1 = __shfl(a1, srcl, 64);
      float t2 = __shfl(a2, srcl, 64);
      float t3 = __shfl(a3, srcl, 64);
      av = kk == 0 ? t0 : (kk == 1 ? t1 : (kk == 2 ? t2 : t3));
    }

    // ---- weighted sum over k: DPP quad butterfly (k = lane bits 0-1) ----
    {
      int b = g >> 10;
      int l = ((g & 1023) << 2) + pp;
      float* ob = out + ((size_t)b * LL + l) * DD + cg * 4;
#pragma unroll
      for (int ks = 0; ks < 16; ++ks) {
        u32x4 u = __builtin_bit_cast(u32x4, aC[ks]);
        float x0 = av * __uint_as_float(u.x << 16);
        float x1 = av * __uint_as_float(u.x & 0xffff0000u);
        float x2 = av * __uint_as_float(u.y << 16);
        float x3 = av * __uint_as_float(u.y & 0xffff0000u);
        float x4 = av * __uint_as_float(u.z << 16);
        float x5 = av * __uint_as_float(u.z & 0xffff0000u);
        float x6 = av * __uint_as_float(u.w << 16);
        float x7 = av * __uint_as_float(u.w & 0xffff0000u);
        x0 = qadd<0xB1>(x0); x1 = qadd<0xB1>(x1);
        x2 = qadd<0xB1>(x2); x3 = qadd<0xB1>(x3);
        x4 = qadd<0xB1>(x4); x5 = qadd<0xB1>(x5);
        x6 = qadd<0xB1>(x6); x7 = qadd<0xB1>(x7);
        x0 = qadd<0x4E>(x0); x1 = qadd<0x4E>(x1);
        x2 = qadd<0x4E>(x2); x3 = qadd<0x4E>(x3);
        x4 = qadd<0x4E>(x4); x5 = qadd<0x4E>(x5);
        x6 = qadd<0x4E>(x6); x7 = qadd<0x4E>(x7);
        if (kk == 0) {
          f32x4 o0 = {x0, x1, x2, x3};
          f32x4 o1 = {x4, x5, x6, x7};
          *(f32x4*)(ob + ks * 32) = o0;
          *(f32x4*)(ob + ks * 32 + 16) = o1;
        }
      }
    }

    // ---- finish next-tile pack; rotate buffers ----
    if (hasNext) {
#pragma unroll
      for (int j2 = 12; j2 < 16; ++j2) packA(rw0[j2 & 3], rw1[j2 & 3], &aN[j2]);
#pragma unroll
      for (int ks = 0; ks < 16; ++ks) aC[ks] = aN[ks];
    }
  }
}

extern "C" void kernel_launch(void* const* d_in, const int* in_sizes, int n_in,
                              void* d_out, int out_size, void* d_ws, size_t ws_size,
                              hipStream_t stream) {
  const float* hs   = (const float*)d_in[0];
  // d_in[1] = mask (int32) — unused: softmax over k is invariant to the
  // per-(b,l) uniform -1e4 shift, so the mask cannot affect x.
  const float* ln_w = (const float*)d_in[2];
  const float* ln_b = (const float*)d_in[3];
  const float* v_w  = (const float*)d_in[4];
  const float* vq   = (const float*)d_in[5];
  float* out = (float*)d_out;

  unsigned int* wf = (unsigned int*)d_ws;          // 128KB fragment-ordered bf16 W_h
  float* qb = (float*)((char*)d_ws + 131072);      // 512B q_bias

  qbias_kernel<<<1, 128, 0, stream>>>(ln_w, ln_b, vq, qb);
  wf_kernel<<<32, 256, 0, stream>>>(ln_w, wf);
  agg_main<<<256, 512, 131072, stream>>>(hs, wf, qb, v_w, out);
}

// Round 4
// 150.527 us; speedup vs baseline: 4.6204x; 4.6204x over previous
//
#include <hip/hip_runtime.h>
#include <hip/hip_bf16.h>
#include <stdint.h>

// Problem constants
#define KK 4
#define BB 16
#define LL 4096
#define DD 512
#define HH 128

typedef __attribute__((ext_vector_type(8))) short bf16x8;
typedef __attribute__((ext_vector_type(4))) float f32x4;
typedef __attribute__((ext_vector_type(4))) unsigned int u32x4;

__device__ __forceinline__ unsigned int pack_bf16(float lo, float hi) {
  unsigned int a = __float_as_uint(lo);
  unsigned int b = __float_as_uint(hi);
  a = (a + 0x7FFFu + ((a >> 16) & 1u)) >> 16;   // RNE f32->bf16
  b = (b + 0x7FFFu + ((b >> 16) & 1u)) >> 16;
  return a | (b << 16);
}

// ---------------- kernel 0a: q_bias = W_q @ vq + ln_b ----------------
__global__ void qbias_kernel(const float* __restrict__ ln_w,
                             const float* __restrict__ ln_b,
                             const float* __restrict__ vq,
                             float* __restrict__ qb) {
  int h = threadIdx.x;
  if (h < HH) {
    float acc = ln_b[h];
    const float* wq = ln_w + (size_t)h * (DD + HH) + DD;
    for (int j = 0; j < HH; ++j) acc = fmaf(wq[j], vq[j], acc);
    qb[h] = acc;
  }
}

// ---------------- kernel 0b: W_h -> fragment-ordered bf16 (natural d) ----
// Chunk gid = (ks*8 + nt)*64 + lane holds 8 bf16 (MFMA B-fragment):
//   element j: W[nt*16 + (lane&15)][ks*32 + (lane>>4)*8 + j]
__global__ void wf_kernel(const float* __restrict__ ln_w,
                          unsigned int* __restrict__ wf) {
  int gid = blockIdx.x * 256 + threadIdx.x;   // 0..8191
  int ks = gid >> 9;
  int nt = (gid >> 6) & 7;
  int lane = gid & 63;
  int h = nt * 16 + (lane & 15);
  int d0 = ks * 32 + (lane >> 4) * 8;
  const float* src = ln_w + (size_t)h * (DD + HH) + d0;
  u32x4 v;
  v.x = pack_bf16(src[0], src[1]);
  v.y = pack_bf16(src[2], src[3]);
  v.z = pack_bf16(src[4], src[5]);
  v.w = pack_bf16(src[6], src[7]);
  *(u32x4*)(wf + (size_t)gid * 4) = v;
}

// ---------------- main fused kernel ----------------
// 256 blocks x 512 threads (1 block/CU, 8 waves), persistent over 32 tiles
// of 8 positions. W split by h across waves (regs). A tile double-buffered
// as bf16 in LDS (2x32KB), reg-staged (issue loads early, ds_write late).
// A rows: row = pos*4 + k (XOR-swizzled by (row&7)<<4). MFMA M-subtiles
// st=0,1 cover rows st*16..+15 -> C/D: pos = st*4 + (lane>>4), k = reg j.
__global__ __launch_bounds__(512) void agg_main(
    const float* __restrict__ hs, const unsigned int* __restrict__ wf,
    const float* __restrict__ qb, const float* __restrict__ vw,
    float* __restrict__ out) {
  extern __shared__ char smem[];
  char* abuf = smem;                             // 2 x 32768 B
  f32x4* spv = (f32x4*)(smem + 65536);           // [8 wv][8 pos] partial s (k in vec)
  float* aarr = (float*)(smem + 65536 + 1024);   // [8 pos][4 k] softmax weights

  const int tid = threadIdx.x;
  const int lane = tid & 63;
  const int wv = tid >> 6;            // 0..7
  const int r = lane & 15;
  const int cg = lane >> 4;

  const int b = blockIdx.x >> 4;
  const int l0b = (blockIdx.x & 15) << 8;        // 256 l per block, 32 tiles of 8

  // ---- W fragments for nt = wv (h in [wv*16, wv*16+16)) ----
  bf16x8 wreg[16];
#pragma unroll
  for (int ks = 0; ks < 16; ++ks)
    wreg[ks] = *(const bf16x8*)(wf + ((size_t)((ks * 8 + wv) * 64 + lane)) * 4);

  const float qbr = qb[wv * 16 + r];
  const float vwr = vw[wv * 16 + r];

  // ---- staging helpers (chunk i: row = i*8+wv, d0 = (lane ^ (row&7))*8) ----
  f32x4 sv[8];
  auto issue_stage = [&](int l0) {
#pragma unroll
    for (int i = 0; i < 4; ++i) {
      int row = i * 8 + wv;
      int k = row & 3, pos = row >> 2;
      int d0 = (lane ^ (row & 7)) * 8;
      const float* p = hs + (((size_t)(k * BB + b)) * LL + l0 + pos) * DD + d0;
      sv[i * 2]     = *(const f32x4*)(p);
      sv[i * 2 + 1] = *(const f32x4*)(p + 4);
    }
  };
  auto write_stage = [&](char* dst) {
#pragma unroll
    for (int i = 0; i < 4; ++i) {
      u32x4 pk;
      pk.x = pack_bf16(sv[i * 2].x, sv[i * 2].y);
      pk.y = pack_bf16(sv[i * 2].z, sv[i * 2].w);
      pk.z = pack_bf16(sv[i * 2 + 1].x, sv[i * 2 + 1].y);
      pk.w = pack_bf16(sv[i * 2 + 1].z, sv[i * 2 + 1].w);
      *(u32x4*)(dst + i * 8192 + tid * 16) = pk;   // physical = logical ^ ((row&7)<<4)
    }
  };

  // ---- prologue: stage tile 0 ----
  issue_stage(l0b);
  write_stage(abuf);
  __syncthreads();

  for (int t = 0; t < 32; ++t) {
    const int l0 = l0b + t * 8;
    char* cur = abuf + (t & 1) * 32768;
    char* nxt = abuf + ((t & 1) ^ 1) * 32768;

    // issue next tile's global loads NOW (drain under compute)
    if (t < 31) issue_stage(l0 + 8);

    // ---- GEMM: 2 M-subtiles x 16 K-steps ----
    f32x4 acc0 = {0.f, 0.f, 0.f, 0.f};
    f32x4 acc1 = {0.f, 0.f, 0.f, 0.f};
    const int swz = (r & 7) << 4;     // rows st*16+r share (row&7)=r&7
#pragma unroll
    for (int ks = 0; ks < 16; ++ks) {
      int inner = (ks * 64 + cg * 16) ^ swz;
      bf16x8 a0 = *(const bf16x8*)(cur + r * 1024 + inner);
      bf16x8 a1 = *(const bf16x8*)(cur + (16 + r) * 1024 + inner);
      acc0 = __builtin_amdgcn_mfma_f32_16x16x32_bf16(a0, wreg[ks], acc0, 0, 0, 0);
      acc1 = __builtin_amdgcn_mfma_f32_16x16x32_bf16(a1, wreg[ks], acc1, 0, 0, 0);
    }

    // ---- partial scores: p = vw[h]*tanh(z + qb[h]), reduce over 16 h ----
    float ps[8];
#pragma unroll
    for (int st = 0; st < 2; ++st) {
      f32x4 acc = st ? acc1 : acc0;
#pragma unroll
      for (int j = 0; j < 4; ++j) {
        float z = acc[j] + qbr;
        z = fminf(15.f, fmaxf(-15.f, z));
        float e = __expf(-2.f * z);
        float th = (1.f - e) * __builtin_amdgcn_rcpf(1.f + e);
        ps[st * 4 + j] = vwr * th;
      }
    }
#pragma unroll
    for (int m = 1; m < 16; m <<= 1) {
#pragma unroll
      for (int q = 0; q < 8; ++q) ps[q] += __shfl_xor(ps[q], m, 64);
    }
    if (r == 0) {
      f32x4 v0 = {ps[0], ps[1], ps[2], ps[3]};
      f32x4 v1 = {ps[4], ps[5], ps[6], ps[7]};
      spv[wv * 8 + cg] = v0;          // pos = 0*4+cg, components = k
      spv[wv * 8 + 4 + cg] = v1;      // pos = 1*4+cg
    }
    __syncthreads();

    // ---- softmax over k per pos (mask dropped: uniform shift, invariant) ----
    if (tid < 8) {
      f32x4 s = spv[tid];
#pragma unroll
      for (int w2 = 1; w2 < 8; ++w2) s += spv[w2 * 8 + tid];
      float mx = fmaxf(fmaxf(s.x, s.y), fmaxf(s.z, s.w));
      float e0 = __expf(s.x - mx), e1 = __expf(s.y - mx);
      float e2 = __expf(s.z - mx), e3 = __expf(s.w - mx);
      float inv = 1.f / (e0 + e1 + e2 + e3);
      f32x4 a4 = {e0 * inv, e1 * inv, e2 * inv, e3 * inv};
      *(f32x4*)(aarr + tid * 4) = a4;
    }
    __syncthreads();

    // ---- weighted sum: wave wv handles pos = wv; x[d] = sum_k a_k*hs_k[d] ----
    {
      const float* af = aarr + wv * 4;
      float a0 = af[0], a1 = af[1], a2 = af[2], a3 = af[3];
      float x[8];
#pragma unroll
      for (int j = 0; j < 8; ++j) x[j] = 0.f;
#pragma unroll
      for (int k = 0; k < 4; ++k) {
        int row = wv * 4 + k;
        float ak = k == 0 ? a0 : (k == 1 ? a1 : (k == 2 ? a2 : a3));
        u32x4 u = *(const u32x4*)(cur + row * 1024 + ((lane * 16) ^ ((row & 7) << 4)));
        x[0] = fmaf(ak, __uint_as_float(u.x << 16), x[0]);
        x[1] = fmaf(ak, __uint_as_float(u.x & 0xffff0000u), x[1]);
        x[2] = fmaf(ak, __uint_as_float(u.y << 16), x[2]);
        x[3] = fmaf(ak, __uint_as_float(u.y & 0xffff0000u), x[3]);
        x[4] = fmaf(ak, __uint_as_float(u.z << 16), x[4]);
        x[5] = fmaf(ak, __uint_as_float(u.z & 0xffff0000u), x[5]);
        x[6] = fmaf(ak, __uint_as_float(u.w << 16), x[6]);
        x[7] = fmaf(ak, __uint_as_float(u.w & 0xffff0000u), x[7]);
      }
      float* ob = out + (((size_t)b) * LL + l0 + wv) * DD + lane * 8;
      f32x4 o0 = {x[0], x[1], x[2], x[3]};
      f32x4 o1 = {x[4], x[5], x[6], x[7]};
      *(f32x4*)(ob) = o0;
      *(f32x4*)(ob + 4) = o1;
    }

    // ---- publish next tile's buffer ----
    if (t < 31) write_stage(nxt);
    __syncthreads();
  }
}

extern "C" void kernel_launch(void* const* d_in, const int* in_sizes, int n_in,
                              void* d_out, int out_size, void* d_ws, size_t ws_size,
                              hipStream_t stream) {
  const float* hs   = (const float*)d_in[0];
  // d_in[1] = mask (int32) — unused: softmax over k is invariant to the
  // per-(b,l) uniform -1e4 shift, so the mask cannot affect x.
  const float* ln_w = (const float*)d_in[2];
  const float* ln_b = (const float*)d_in[3];
  const float* v_w  = (const float*)d_in[4];
  const float* vq   = (const float*)d_in[5];
  float* out = (float*)d_out;

  unsigned int* wf = (unsigned int*)d_ws;          // 128KB fragment-ordered bf16 W_h
  float* qb = (float*)((char*)d_ws + 131072);      // 512B q_bias

  qbias_kernel<<<1, 128, 0, stream>>>(ln_w, ln_b, vq, qb);
  wf_kernel<<<32, 256, 0, stream>>>(ln_w, wf);
  agg_main<<<256, 512, 66688, stream>>>(hs, wf, qb, v_w, out);
}